// Round 1
// baseline (12530.483 us; speedup 1.0000x reference)
//
#include <hip/hip_runtime.h>
#include <hip/hip_bf16.h>
#include <stdint.h>

#define D_IN 128
#define D_H 256
#define NLAYERS 5

typedef __bf16 bf16x8 __attribute__((ext_vector_type(8)));
typedef float f32x4 __attribute__((ext_vector_type(4)));

__device__ inline __bf16 f2bf(float f) {
  __hip_bfloat16 h = __float2bfloat16(f);
  __bf16 r;
  __builtin_memcpy(&r, &h, sizeof(r));
  return r;
}

__global__ void f32_to_bf16_kernel(const float* __restrict__ in,
                                   __hip_bfloat16* __restrict__ out, int n) {
  int gid = blockIdx.x * blockDim.x + threadIdx.x;
  if (gid < n) out[gid] = __float2bfloat16(in[gid]);
}

// pre[n][j] = (1 + eps) * h[n][j], vectorized float4
__global__ void scale_init(const float* __restrict__ in, float* __restrict__ out,
                           const float* __restrict__ eps_all, int layer, int n4) {
  int gid = blockIdx.x * blockDim.x + threadIdx.x;
  if (gid >= n4) return;
  float s = 1.0f + eps_all[layer];
  f32x4 v = reinterpret_cast<const f32x4*>(in)[gid];
  reinterpret_cast<f32x4*>(out)[gid] = v * s;
}

// pre[dst[e]][j] += h[src[e]][j]  (atomic scatter-sum over edges)
// each thread: one edge x 4 consecutive features
__global__ void scatter_add(const float* __restrict__ h, const int* __restrict__ ei,
                            float* __restrict__ pre, int E, int d, int log2c) {
  int e = blockIdx.x * (256 >> log2c) + (threadIdx.x >> log2c);
  if (e >= E) return;
  int chunks = d >> 2;
  int j4 = (threadIdx.x & (chunks - 1)) << 2;
  int s = ei[e];
  int t = ei[E + e];
  const float4 v = *reinterpret_cast<const float4*>(h + (size_t)s * d + j4);
  float* p = pre + (size_t)t * d + j4;
  atomicAdd(p + 0, v.x);
  atomicAdd(p + 1, v.y);
  atomicAdd(p + 2, v.z);
  atomicAdd(p + 3, v.w);
}

// C[n][o] = relu( A[n][:] . W[o][:] + bias[o] )   (torch Linear: y = x @ W.T + b)
// A: [Nrows x K] (fp32 or bf16), W: [256 x K] bf16, Out: [Nrows x 256] (bf16 or fp32)
// block = 256 thr = 4 waves; block covers 32 rows x 256 cols; wave covers 32x64.
// mfma_f32_16x16x32_bf16: a/b frag: row/col = lane&15, k = (lane>>4)*8 + j;
// C/D frag: col = lane&15, row = (lane>>4)*4 + reg.
template <bool A_BF16, bool OUT_BF16>
__global__ __launch_bounds__(256) void gin_gemm(const void* __restrict__ Ap,
                                                const __hip_bfloat16* __restrict__ Wb,
                                                const float* __restrict__ bias,
                                                void* __restrict__ Outp,
                                                int Nrows, int K) {
  const int lane = threadIdx.x & 63;
  const int wave = threadIdx.x >> 6;
  const int l15 = lane & 15;
  const int kg = lane >> 4;  // 0..3
  const int row0 = blockIdx.x * 32;
  const int col0 = wave * 64;

  f32x4 acc[2][4];
#pragma unroll
  for (int rt = 0; rt < 2; ++rt)
#pragma unroll
    for (int ct = 0; ct < 4; ++ct) acc[rt][ct] = 0.0f;

  bf16x8 zfrag;
#pragma unroll
  for (int i = 0; i < 8; ++i) zfrag[i] = f2bf(0.0f);

  for (int k = 0; k < K; k += 32) {
    bf16x8 afr[2];
#pragma unroll
    for (int rt = 0; rt < 2; ++rt) {
      int m = row0 + rt * 16 + l15;
      int kk = k + kg * 8;
      if (m < Nrows) {
        if (A_BF16) {
          afr[rt] = *reinterpret_cast<const bf16x8*>(
              (const __hip_bfloat16*)Ap + (size_t)m * K + kk);
        } else {
          const float* a = (const float*)Ap + (size_t)m * K + kk;
          f32x4 lo = *reinterpret_cast<const f32x4*>(a);
          f32x4 hi = *reinterpret_cast<const f32x4*>(a + 4);
          bf16x8 t;
#pragma unroll
          for (int i = 0; i < 4; ++i) {
            t[i] = f2bf(lo[i]);
            t[i + 4] = f2bf(hi[i]);
          }
          afr[rt] = t;
        }
      } else {
        afr[rt] = zfrag;
      }
    }
    bf16x8 bfr[4];
#pragma unroll
    for (int ct = 0; ct < 4; ++ct) {
      int o = col0 + ct * 16 + l15;
      bfr[ct] = *reinterpret_cast<const bf16x8*>(Wb + (size_t)o * K + k + kg * 8);
    }
#pragma unroll
    for (int rt = 0; rt < 2; ++rt)
#pragma unroll
      for (int ct = 0; ct < 4; ++ct)
        acc[rt][ct] = __builtin_amdgcn_mfma_f32_16x16x32_bf16(afr[rt], bfr[ct],
                                                              acc[rt][ct], 0, 0, 0);
  }

#pragma unroll
  for (int rt = 0; rt < 2; ++rt) {
#pragma unroll
    for (int ct = 0; ct < 4; ++ct) {
      int col = col0 + ct * 16 + l15;
      float bv = bias[col];
#pragma unroll
      for (int i = 0; i < 4; ++i) {
        int row = row0 + rt * 16 + kg * 4 + i;
        if (row < Nrows) {
          float v = acc[rt][ct][i] + bv;
          v = fmaxf(v, 0.0f);
          if (OUT_BF16)
            ((__hip_bfloat16*)Outp)[(size_t)row * D_H + col] = __float2bfloat16(v);
          else
            ((float*)Outp)[(size_t)row * D_H + col] = v;
        }
      }
    }
  }
}

extern "C" void kernel_launch(void* const* d_in, const int* in_sizes, int n_in,
                              void* d_out, int out_size, void* d_ws, size_t ws_size,
                              hipStream_t stream) {
  const float* x = (const float*)d_in[0];
  const int* ei = (const int*)d_in[1];  // [2, E]: row0 = src, row1 = dst
  const float* eps_all = (const float*)d_in[2];
  const float* w0_l0 = (const float*)d_in[3];
  const float* b0_l0 = (const float*)d_in[4];
  const float* w1_l0 = (const float*)d_in[5];
  const float* b1_l0 = (const float*)d_in[6];
  const float* w0_rest = (const float*)d_in[7];
  const float* b0_rest = (const float*)d_in[8];
  const float* w1_rest = (const float*)d_in[9];
  const float* b1_rest = (const float*)d_in[10];

  const int N = in_sizes[0] / D_IN;  // 50000
  const int E = in_sizes[1] / 2;     // 800000

  char* ws = (char*)d_ws;
  const size_t nodes_f32 = (size_t)N * D_H * sizeof(float);   // 51.2 MB
  float* h = (float*)ws;                                      // layer outputs
  float* pre = (float*)(ws + nodes_f32);                      // (1+eps)x + aggr
  __hip_bfloat16* mid = (__hip_bfloat16*)(ws + 2 * nodes_f32);  // gemm1 out, bf16
  __hip_bfloat16* wbf =
      (__hip_bfloat16*)(ws + 2 * nodes_f32 + (size_t)N * D_H * sizeof(__hip_bfloat16));

  __hip_bfloat16* w0_l0_bf = wbf;                      // 256*128
  __hip_bfloat16* w1_l0_bf = wbf + 32768;              // 256*256
  __hip_bfloat16* w0_rest_bf = wbf + 32768 + 65536;    // 4*256*256
  __hip_bfloat16* w1_rest_bf = w0_rest_bf + 262144;    // 4*256*256

  f32_to_bf16_kernel<<<(32768 + 255) / 256, 256, 0, stream>>>(w0_l0, w0_l0_bf, 32768);
  f32_to_bf16_kernel<<<(65536 + 255) / 256, 256, 0, stream>>>(w1_l0, w1_l0_bf, 65536);
  f32_to_bf16_kernel<<<(262144 + 255) / 256, 256, 0, stream>>>(w0_rest, w0_rest_bf, 262144);
  f32_to_bf16_kernel<<<(262144 + 255) / 256, 256, 0, stream>>>(w1_rest, w1_rest_bf, 262144);

  const int gemmBlocks = (N + 31) / 32;

  for (int layer = 0; layer < NLAYERS; ++layer) {
    const float* hin = (layer == 0) ? x : h;
    const int din = (layer == 0) ? D_IN : D_H;
    const __hip_bfloat16* w0 =
        (layer == 0) ? w0_l0_bf : w0_rest_bf + (size_t)(layer - 1) * 65536;
    const float* b0 = (layer == 0) ? b0_l0 : b0_rest + (size_t)(layer - 1) * 256;
    const __hip_bfloat16* w1 =
        (layer == 0) ? w1_l0_bf : w1_rest_bf + (size_t)(layer - 1) * 65536;
    const float* b1 = (layer == 0) ? b1_l0 : b1_rest + (size_t)(layer - 1) * 256;
    float* hout = (layer == NLAYERS - 1) ? (float*)d_out : h;

    const int n4 = N * din / 4;
    scale_init<<<(n4 + 255) / 256, 256, 0, stream>>>(hin, pre, eps_all, layer, n4);

    const int log2c = (din == 256) ? 6 : 5;  // 4B-chunks per edge = din/4
    const int epb = 256 >> log2c;            // edges per block
    scatter_add<<<(E + epb - 1) / epb, 256, 0, stream>>>(hin, ei, pre, E, din, log2c);

    gin_gemm<false, true><<<gemmBlocks, 256, 0, stream>>>(pre, w0, b0, mid, N, din);
    gin_gemm<true, false><<<gemmBlocks, 256, 0, stream>>>(mid, w1, b1, hout, N, D_H);
  }
}

// Round 2
// 931.977 us; speedup vs baseline: 13.4450x; 13.4450x over previous
//
#include <hip/hip_runtime.h>
#include <hip/hip_bf16.h>
#include <stdint.h>

#define D_IN 128
#define D_H 256
#define NLAYERS 5

typedef __bf16 bf16x8 __attribute__((ext_vector_type(8)));
typedef float f32x4 __attribute__((ext_vector_type(4)));

__device__ inline __bf16 f2bf(float f) {
  __hip_bfloat16 h = __float2bfloat16(f);
  __bf16 r;
  __builtin_memcpy(&r, &h, sizeof(r));
  return r;
}

__device__ inline unsigned short bfbits(float f) {
  __hip_bfloat16 h = __float2bfloat16(f);
  unsigned short s;
  __builtin_memcpy(&s, &h, 2);
  return s;
}

__device__ inline float bf2f(unsigned short u) {
  return __uint_as_float((unsigned)u << 16);
}

__global__ void f32_to_bf16_kernel(const float* __restrict__ in,
                                   __hip_bfloat16* __restrict__ out, int n) {
  int gid = blockIdx.x * blockDim.x + threadIdx.x;
  if (gid < n) out[gid] = __float2bfloat16(in[gid]);
}

__global__ void zero_ints(int* __restrict__ p, int n) {
  int i = blockIdx.x * blockDim.x + threadIdx.x;
  if (i < n) p[i] = 0;
}

// ---- CSR build (per call; int atomics only) ----
__global__ void hist_kernel(const int* __restrict__ ei, int E, int* __restrict__ deg) {
  int e = blockIdx.x * blockDim.x + threadIdx.x;
  if (e < E) atomicAdd(&deg[ei[E + e]], 1);
}

// single-block exclusive scan over N elements (N ~ 50000)
__global__ __launch_bounds__(1024) void scan_exclusive(const int* __restrict__ deg,
                                                       int* __restrict__ row_start,
                                                       int N) {
  __shared__ int sm[1024];
  __shared__ int carry_sh;
  const int tid = threadIdx.x;
  if (tid == 0) carry_sh = 0;
  __syncthreads();
  for (int base = 0; base < N; base += 1024) {
    int v = (base + tid < N) ? deg[base + tid] : 0;
    sm[tid] = v;
    __syncthreads();
    for (int off = 1; off < 1024; off <<= 1) {
      int t = (tid >= off) ? sm[tid - off] : 0;
      __syncthreads();
      sm[tid] += t;
      __syncthreads();
    }
    int incl = sm[tid];
    int carry = carry_sh;
    if (base + tid < N) row_start[base + tid] = carry + incl - v;
    __syncthreads();
    if (tid == 1023) carry_sh = carry + sm[1023];
    __syncthreads();
  }
}

__global__ void fill_kernel(const int* __restrict__ ei, int E,
                            const int* __restrict__ row_start,
                            int* __restrict__ cursor, int* __restrict__ csr) {
  int e = blockIdx.x * blockDim.x + threadIdx.x;
  if (e >= E) return;
  int d = ei[E + e];
  int p = atomicAdd(&cursor[d], 1);
  csr[row_start[d] + p] = ei[e];
}

// ---- fused aggregation: pre[n] = bf16( (1+eps)*h[n] + sum_{s in in(n)} h[s] ) ----
// one wave per node; lane holds D/64 features.
// IN_F32: input rows are fp32 (layer 0, D=128); else bf16 (D=256).
template <int D, bool IN_F32>
__global__ __launch_bounds__(256) void aggregate(const void* __restrict__ hin,
                                                 const int* __restrict__ csr,
                                                 const int* __restrict__ row_start,
                                                 const int* __restrict__ deg,
                                                 const float* __restrict__ eps_all,
                                                 int layer,
                                                 unsigned short* __restrict__ pre,
                                                 int N) {
  const int wave = threadIdx.x >> 6;
  const int lane = threadIdx.x & 63;
  const int node = blockIdx.x * 4 + wave;
  if (node >= N) return;
  constexpr int EPL = D / 64;  // 2 (f32 layer0) or 4 (bf16)
  float acc[EPL];
#pragma unroll
  for (int i = 0; i < EPL; ++i) acc[i] = 0.0f;

  const int start = row_start[node];
  const int cnt = deg[node];

  if (IN_F32) {
    const float* hf = (const float*)hin;
    int i = 0;
    for (; i + 1 < cnt; i += 2) {
      int s0 = csr[start + i];
      int s1 = csr[start + i + 1];
      float2 v0 = *reinterpret_cast<const float2*>(hf + (size_t)s0 * D + lane * 2);
      float2 v1 = *reinterpret_cast<const float2*>(hf + (size_t)s1 * D + lane * 2);
      acc[0] += v0.x + v1.x;
      acc[1] += v0.y + v1.y;
    }
    if (i < cnt) {
      int s0 = csr[start + i];
      float2 v0 = *reinterpret_cast<const float2*>(hf + (size_t)s0 * D + lane * 2);
      acc[0] += v0.x;
      acc[1] += v0.y;
    }
    float epsv = 1.0f + eps_all[layer];
    float2 self = *reinterpret_cast<const float2*>(hf + (size_t)node * D + lane * 2);
    acc[0] += epsv * self.x;
    acc[1] += epsv * self.y;
    ushort2 o;
    o.x = bfbits(acc[0]);
    o.y = bfbits(acc[1]);
    *reinterpret_cast<ushort2*>(pre + (size_t)node * D + lane * 2) = o;
  } else {
    const unsigned short* hb = (const unsigned short*)hin;
    int i = 0;
    for (; i + 1 < cnt; i += 2) {
      int s0 = csr[start + i];
      int s1 = csr[start + i + 1];
      ushort4 u0 = *reinterpret_cast<const ushort4*>(hb + (size_t)s0 * D + lane * 4);
      ushort4 u1 = *reinterpret_cast<const ushort4*>(hb + (size_t)s1 * D + lane * 4);
      acc[0] += bf2f(u0.x) + bf2f(u1.x);
      acc[1] += bf2f(u0.y) + bf2f(u1.y);
      acc[2] += bf2f(u0.z) + bf2f(u1.z);
      acc[3] += bf2f(u0.w) + bf2f(u1.w);
    }
    if (i < cnt) {
      int s0 = csr[start + i];
      ushort4 u0 = *reinterpret_cast<const ushort4*>(hb + (size_t)s0 * D + lane * 4);
      acc[0] += bf2f(u0.x);
      acc[1] += bf2f(u0.y);
      acc[2] += bf2f(u0.z);
      acc[3] += bf2f(u0.w);
    }
    float epsv = 1.0f + eps_all[layer];
    ushort4 su = *reinterpret_cast<const ushort4*>(hb + (size_t)node * D + lane * 4);
    acc[0] += epsv * bf2f(su.x);
    acc[1] += epsv * bf2f(su.y);
    acc[2] += epsv * bf2f(su.z);
    acc[3] += epsv * bf2f(su.w);
    ushort4 o;
    o.x = bfbits(acc[0]);
    o.y = bfbits(acc[1]);
    o.z = bfbits(acc[2]);
    o.w = bfbits(acc[3]);
    *reinterpret_cast<ushort4*>(pre + (size_t)node * D + lane * 4) = o;
  }
}

// C[n][o] = relu( A[n][:] . W[o][:] + bias[o] )   (torch Linear: y = x @ W.T + b)
// A: [Nrows x K] bf16, W: [256 x K] bf16, Out: [Nrows x 256] (bf16 or fp32)
// block = 256 thr = 4 waves; block covers 32 rows x 256 cols; wave covers 32x64.
template <bool OUT_BF16>
__global__ __launch_bounds__(256) void gin_gemm(const __hip_bfloat16* __restrict__ Ap,
                                                const __hip_bfloat16* __restrict__ Wb,
                                                const float* __restrict__ bias,
                                                void* __restrict__ Outp,
                                                int Nrows, int K) {
  const int lane = threadIdx.x & 63;
  const int wave = threadIdx.x >> 6;
  const int l15 = lane & 15;
  const int kg = lane >> 4;  // 0..3
  const int row0 = blockIdx.x * 32;
  const int col0 = wave * 64;

  f32x4 acc[2][4];
#pragma unroll
  for (int rt = 0; rt < 2; ++rt)
#pragma unroll
    for (int ct = 0; ct < 4; ++ct) acc[rt][ct] = 0.0f;

  bf16x8 zfrag;
#pragma unroll
  for (int i = 0; i < 8; ++i) zfrag[i] = f2bf(0.0f);

  for (int k = 0; k < K; k += 32) {
    bf16x8 afr[2];
#pragma unroll
    for (int rt = 0; rt < 2; ++rt) {
      int m = row0 + rt * 16 + l15;
      int kk = k + kg * 8;
      afr[rt] = (m < Nrows)
                    ? *reinterpret_cast<const bf16x8*>(Ap + (size_t)m * K + kk)
                    : zfrag;
    }
    bf16x8 bfr[4];
#pragma unroll
    for (int ct = 0; ct < 4; ++ct) {
      int o = col0 + ct * 16 + l15;
      bfr[ct] = *reinterpret_cast<const bf16x8*>(Wb + (size_t)o * K + k + kg * 8);
    }
#pragma unroll
    for (int rt = 0; rt < 2; ++rt)
#pragma unroll
      for (int ct = 0; ct < 4; ++ct)
        acc[rt][ct] = __builtin_amdgcn_mfma_f32_16x16x32_bf16(afr[rt], bfr[ct],
                                                              acc[rt][ct], 0, 0, 0);
  }

#pragma unroll
  for (int rt = 0; rt < 2; ++rt) {
#pragma unroll
    for (int ct = 0; ct < 4; ++ct) {
      int col = col0 + ct * 16 + l15;
      float bv = bias[col];
#pragma unroll
      for (int i = 0; i < 4; ++i) {
        int row = row0 + rt * 16 + kg * 4 + i;
        if (row < Nrows) {
          float v = fmaxf(acc[rt][ct][i] + bv, 0.0f);
          if (OUT_BF16)
            ((__hip_bfloat16*)Outp)[(size_t)row * D_H + col] = __float2bfloat16(v);
          else
            ((float*)Outp)[(size_t)row * D_H + col] = v;
        }
      }
    }
  }
}

extern "C" void kernel_launch(void* const* d_in, const int* in_sizes, int n_in,
                              void* d_out, int out_size, void* d_ws, size_t ws_size,
                              hipStream_t stream) {
  const float* x = (const float*)d_in[0];
  const int* ei = (const int*)d_in[1];  // [2, E]: row0 = src, row1 = dst
  const float* eps_all = (const float*)d_in[2];
  const float* w0_l0 = (const float*)d_in[3];
  const float* b0_l0 = (const float*)d_in[4];
  const float* w1_l0 = (const float*)d_in[5];
  const float* b1_l0 = (const float*)d_in[6];
  const float* w0_rest = (const float*)d_in[7];
  const float* b0_rest = (const float*)d_in[8];
  const float* w1_rest = (const float*)d_in[9];
  const float* b1_rest = (const float*)d_in[10];

  const int N = in_sizes[0] / D_IN;  // 50000
  const int E = in_sizes[1] / 2;     // 800000

  char* ws = (char*)d_ws;
  const size_t node_bf = (size_t)N * D_H * sizeof(unsigned short);  // 25.6 MB
  unsigned short* h = (unsigned short*)ws;           // layer outputs (bf16)
  unsigned short* pre = (unsigned short*)(ws + node_bf);
  __hip_bfloat16* mid = (__hip_bfloat16*)(ws + 2 * node_bf);
  char* p = ws + 3 * node_bf;
  __hip_bfloat16* wbf = (__hip_bfloat16*)p;
  p += (32768 + 65536 + 2 * 262144) * sizeof(__hip_bfloat16);  // 1.25 MB
  int* deg = (int*)p;        // [N]
  int* cursor = deg + N;     // [N]
  int* row_start = cursor + N;  // [N]
  int* csr = row_start + N;  // [E]

  __hip_bfloat16* w0_l0_bf = wbf;
  __hip_bfloat16* w1_l0_bf = wbf + 32768;
  __hip_bfloat16* w0_rest_bf = wbf + 32768 + 65536;
  __hip_bfloat16* w1_rest_bf = w0_rest_bf + 262144;

  // weight conversion
  f32_to_bf16_kernel<<<(32768 + 255) / 256, 256, 0, stream>>>(w0_l0, w0_l0_bf, 32768);
  f32_to_bf16_kernel<<<(65536 + 255) / 256, 256, 0, stream>>>(w1_l0, w1_l0_bf, 65536);
  f32_to_bf16_kernel<<<(262144 + 255) / 256, 256, 0, stream>>>(w0_rest, w0_rest_bf, 262144);
  f32_to_bf16_kernel<<<(262144 + 255) / 256, 256, 0, stream>>>(w1_rest, w1_rest_bf, 262144);

  // CSR build
  zero_ints<<<(2 * N + 255) / 256, 256, 0, stream>>>(deg, 2 * N);  // deg + cursor
  hist_kernel<<<(E + 255) / 256, 256, 0, stream>>>(ei, E, deg);
  scan_exclusive<<<1, 1024, 0, stream>>>(deg, row_start, N);
  fill_kernel<<<(E + 255) / 256, 256, 0, stream>>>(ei, E, row_start, cursor, csr);

  const int gemmBlocks = (N + 31) / 32;
  const int aggBlocks = (N + 3) / 4;

  for (int layer = 0; layer < NLAYERS; ++layer) {
    const int din = (layer == 0) ? D_IN : D_H;
    const __hip_bfloat16* w0 =
        (layer == 0) ? w0_l0_bf : w0_rest_bf + (size_t)(layer - 1) * 65536;
    const float* b0 = (layer == 0) ? b0_l0 : b0_rest + (size_t)(layer - 1) * 256;
    const __hip_bfloat16* w1 =
        (layer == 0) ? w1_l0_bf : w1_rest_bf + (size_t)(layer - 1) * 65536;
    const float* b1 = (layer == 0) ? b1_l0 : b1_rest + (size_t)(layer - 1) * 256;
    void* hout = (layer == NLAYERS - 1) ? d_out : (void*)h;

    if (layer == 0) {
      aggregate<D_IN, true><<<aggBlocks, 256, 0, stream>>>(
          x, csr, row_start, deg, eps_all, layer, pre, N);
    } else {
      aggregate<D_H, false><<<aggBlocks, 256, 0, stream>>>(
          h, csr, row_start, deg, eps_all, layer, pre, N);
    }

    gin_gemm<true><<<gemmBlocks, 256, 0, stream>>>(
        (const __hip_bfloat16*)pre, w0, b0, mid, N, din);
    if (layer == NLAYERS - 1)
      gin_gemm<false><<<gemmBlocks, 256, 0, stream>>>(mid, w1, b1, hout, N, D_H);
    else
      gin_gemm<true><<<gemmBlocks, 256, 0, stream>>>(mid, w1, b1, hout, N, D_H);
  }
}

// Round 3
// 726.409 us; speedup vs baseline: 17.2499x; 1.2830x over previous
//
#include <hip/hip_runtime.h>
#include <hip/hip_bf16.h>
#include <stdint.h>

#define D_IN 128
#define D_H 256
#define NLAYERS 5

typedef __bf16 bf16x8 __attribute__((ext_vector_type(8)));
typedef __bf16 bf16x4 __attribute__((ext_vector_type(4)));
typedef float f32x4 __attribute__((ext_vector_type(4)));
typedef unsigned short u16x8 __attribute__((ext_vector_type(8)));

// LDS mid-tile row stride in ushorts: 260 u16 = 520 B = 130 dwords.
// 130 mod 8 == 2 -> the four kg-groups of the epilogue write land on
// disjoint bank octets; 520 B is 8B-aligned so GEMM1 A-frags read as 2x b64.
#define MID_STRIDE 260

__device__ inline __bf16 f2bf(float f) {
  __hip_bfloat16 h = __float2bfloat16(f);
  __bf16 r;
  __builtin_memcpy(&r, &h, sizeof(r));
  return r;
}

__device__ inline unsigned short bfbits(float f) {
  __hip_bfloat16 h = __float2bfloat16(f);
  unsigned short s;
  __builtin_memcpy(&s, &h, 2);
  return s;
}

__device__ inline float bf2f(unsigned short u) {
  return __uint_as_float((unsigned)u << 16);
}

// convert all 4 weight tensors to bf16 in one launch
__global__ void conv_weights(const float* __restrict__ a, const float* __restrict__ b,
                             const float* __restrict__ c, const float* __restrict__ d,
                             __hip_bfloat16* __restrict__ out) {
  int gid = blockIdx.x * blockDim.x + threadIdx.x;
  if (gid >= 622592) return;
  float v;
  if (gid < 32768) v = a[gid];
  else if (gid < 98304) v = b[gid - 32768];
  else if (gid < 360448) v = c[gid - 98304];
  else v = d[gid - 360448];
  out[gid] = __float2bfloat16(v);
}

__global__ void zero_ints(int* __restrict__ p, int n) {
  int i = blockIdx.x * blockDim.x + threadIdx.x;
  if (i < n) p[i] = 0;
}

// ---- CSR build ----
__global__ void hist_kernel(const int* __restrict__ ei, int E, int* __restrict__ deg) {
  int e = blockIdx.x * blockDim.x + threadIdx.x;
  if (e < E) atomicAdd(&deg[ei[E + e]], 1);
}

// hierarchical scan: (1) per-1024-block sums
__global__ __launch_bounds__(256) void block_sums(const int* __restrict__ deg,
                                                  int* __restrict__ bsum, int N) {
  int t = threadIdx.x;
  int idx = blockIdx.x * 1024 + t * 4;
  int4 v = {0, 0, 0, 0};
  if (idx + 3 < N) v = *reinterpret_cast<const int4*>(deg + idx);
  else {
    if (idx + 0 < N) v.x = deg[idx + 0];
    if (idx + 1 < N) v.y = deg[idx + 1];
    if (idx + 2 < N) v.z = deg[idx + 2];
    if (idx + 3 < N) v.w = deg[idx + 3];
  }
  int s = v.x + v.y + v.z + v.w;
#pragma unroll
  for (int off = 32; off > 0; off >>= 1) s += __shfl_down(s, off);
  __shared__ int ws[4];
  int lane = t & 63, w = t >> 6;
  if (lane == 0) ws[w] = s;
  __syncthreads();
  if (t == 0) bsum[blockIdx.x] = ws[0] + ws[1] + ws[2] + ws[3];
}

// (2) exclusive scan of <=64 block sums, single wave
__global__ void scan_bsums(int* __restrict__ bsum, int nb) {
  int t = threadIdx.x;
  int orig = (t < nb) ? bsum[t] : 0;
  int v = orig;
#pragma unroll
  for (int off = 1; off < 64; off <<= 1) {
    int u = __shfl_up(v, off);
    if (t >= off) v += u;
  }
  if (t < nb) bsum[t] = v - orig;  // exclusive
}

// (3) apply: full exclusive scan -> row_start
__global__ __launch_bounds__(256) void scan_apply(const int* __restrict__ deg,
                                                  const int* __restrict__ bsum_ex,
                                                  int* __restrict__ row_start, int N) {
  int t = threadIdx.x;
  int idx = blockIdx.x * 1024 + t * 4;
  int4 v = {0, 0, 0, 0};
  if (idx + 3 < N) v = *reinterpret_cast<const int4*>(deg + idx);
  else {
    if (idx + 0 < N) v.x = deg[idx + 0];
    if (idx + 1 < N) v.y = deg[idx + 1];
    if (idx + 2 < N) v.z = deg[idx + 2];
    if (idx + 3 < N) v.w = deg[idx + 3];
  }
  int s = v.x + v.y + v.z + v.w;
  int lane = t & 63, w = t >> 6;
  int sc = s;
#pragma unroll
  for (int off = 1; off < 64; off <<= 1) {
    int u = __shfl_up(sc, off);
    if (lane >= off) sc += u;
  }
  __shared__ int woff[4];
  if (lane == 63) woff[w] = sc;
  __syncthreads();
  int boff = bsum_ex[blockIdx.x];
#pragma unroll
  for (int i = 0; i < 4; ++i)
    if (i < w) boff += woff[i];
  int ex = boff + sc - s;
  if (idx + 3 < N) {
    int4 o;
    o.x = ex;
    o.y = ex + v.x;
    o.z = ex + v.x + v.y;
    o.w = ex + v.x + v.y + v.z;
    *reinterpret_cast<int4*>(row_start + idx) = o;
  } else {
    if (idx + 0 < N) row_start[idx + 0] = ex;
    if (idx + 1 < N) row_start[idx + 1] = ex + v.x;
    if (idx + 2 < N) row_start[idx + 2] = ex + v.x + v.y;
    if (idx + 3 < N) row_start[idx + 3] = ex + v.x + v.y + v.z;
  }
}

__global__ void fill_kernel(const int* __restrict__ ei, int E,
                            const int* __restrict__ row_start,
                            int* __restrict__ cursor, int* __restrict__ csr) {
  int e = blockIdx.x * blockDim.x + threadIdx.x;
  if (e >= E) return;
  int d = ei[E + e];
  int p = atomicAdd(&cursor[d], 1);
  csr[row_start[d] + p] = ei[e];
}

// ---- fused aggregation: pre[n] = bf16( (1+eps)*h[n] + sum_{s in in(n)} h[s] ) ----
// half-wave (32 lanes) per node; lane holds 16 B of the feature row.
template <int D, bool IN_F32>
__global__ __launch_bounds__(256) void aggregate(const void* __restrict__ hin,
                                                 const int* __restrict__ csr,
                                                 const int* __restrict__ row_start,
                                                 const int* __restrict__ deg,
                                                 const float* __restrict__ eps_all,
                                                 int layer,
                                                 unsigned short* __restrict__ pre,
                                                 int N) {
  const int half = threadIdx.x >> 5;   // 0..7
  const int lane = threadIdx.x & 31;
  const int node = blockIdx.x * 8 + half;
  if (node >= N) return;

  const int start = row_start[node];
  const int cnt = deg[node];

  if (IN_F32) {  // D=128 fp32: lane holds float4
    const float* hf = (const float*)hin;
    f32x4 acc = 0.0f;
    int i = 0;
    for (; i + 1 < cnt; i += 2) {
      int s0 = csr[start + i];
      int s1 = csr[start + i + 1];
      f32x4 v0 = *reinterpret_cast<const f32x4*>(hf + (size_t)s0 * D + lane * 4);
      f32x4 v1 = *reinterpret_cast<const f32x4*>(hf + (size_t)s1 * D + lane * 4);
      acc += v0 + v1;
    }
    if (i < cnt) {
      int s0 = csr[start + i];
      acc += *reinterpret_cast<const f32x4*>(hf + (size_t)s0 * D + lane * 4);
    }
    float epsv = 1.0f + eps_all[layer];
    f32x4 self = *reinterpret_cast<const f32x4*>(hf + (size_t)node * D + lane * 4);
    acc += self * epsv;
    ushort4 o;
    o.x = bfbits(acc[0]);
    o.y = bfbits(acc[1]);
    o.z = bfbits(acc[2]);
    o.w = bfbits(acc[3]);
    *reinterpret_cast<ushort4*>(pre + (size_t)node * D + lane * 4) = o;
  } else {  // D=256 bf16: lane holds ushort8
    const unsigned short* hb = (const unsigned short*)hin;
    float acc[8];
#pragma unroll
    for (int j = 0; j < 8; ++j) acc[j] = 0.0f;
    int i = 0;
    for (; i + 1 < cnt; i += 2) {
      int s0 = csr[start + i];
      int s1 = csr[start + i + 1];
      u16x8 u0 = *reinterpret_cast<const u16x8*>(hb + (size_t)s0 * D + lane * 8);
      u16x8 u1 = *reinterpret_cast<const u16x8*>(hb + (size_t)s1 * D + lane * 8);
#pragma unroll
      for (int j = 0; j < 8; ++j) acc[j] += bf2f(u0[j]) + bf2f(u1[j]);
    }
    if (i < cnt) {
      int s0 = csr[start + i];
      u16x8 u0 = *reinterpret_cast<const u16x8*>(hb + (size_t)s0 * D + lane * 8);
#pragma unroll
      for (int j = 0; j < 8; ++j) acc[j] += bf2f(u0[j]);
    }
    float epsv = 1.0f + eps_all[layer];
    u16x8 su = *reinterpret_cast<const u16x8*>(hb + (size_t)node * D + lane * 8);
    u16x8 o;
#pragma unroll
    for (int j = 0; j < 8; ++j) o[j] = bfbits(acc[j] + epsv * bf2f(su[j]));
    *reinterpret_cast<u16x8*>(pre + (size_t)node * D + lane * 8) = o;
  }
}

// ---- fused 2-layer MLP: out = relu( relu(A@W0.T+b0) @ W1.T + b1 ) ----
// A: [Nrows x K0] bf16; W0: [256 x K0] bf16; W1: [256 x 256] bf16.
// block = 256 thr = 4 waves; covers 32 rows x 256 cols; wave does 32x64.
// mfma_f32_16x16x32_bf16 frag maps: A/B row/col = lane&15, k = (lane>>4)*8 + j;
// C/D: col = lane&15, row = (lane>>4)*4 + reg.
template <int K0, bool OUT_BF16>
__global__ __launch_bounds__(256) void gin_mlp(const __hip_bfloat16* __restrict__ Ap,
                                               const __hip_bfloat16* __restrict__ W0,
                                               const float* __restrict__ b0,
                                               const __hip_bfloat16* __restrict__ W1,
                                               const float* __restrict__ b1,
                                               void* __restrict__ Outp, int Nrows) {
  __shared__ unsigned short mid[32 * MID_STRIDE];

  const int lane = threadIdx.x & 63;
  const int wave = threadIdx.x >> 6;
  const int l15 = lane & 15;
  const int kg = lane >> 4;  // 0..3
  const int row0 = blockIdx.x * 32;
  const int col0 = wave * 64;

  bf16x8 zfrag;
#pragma unroll
  for (int i = 0; i < 8; ++i) zfrag[i] = f2bf(0.0f);

  // ---- GEMM0 ----
  f32x4 acc0[2][4];
#pragma unroll
  for (int rt = 0; rt < 2; ++rt)
#pragma unroll
    for (int ct = 0; ct < 4; ++ct) acc0[rt][ct] = 0.0f;

  for (int k = 0; k < K0; k += 32) {
    bf16x8 afr[2];
#pragma unroll
    for (int rt = 0; rt < 2; ++rt) {
      int m = row0 + rt * 16 + l15;
      afr[rt] = (m < Nrows)
                    ? *reinterpret_cast<const bf16x8*>(Ap + (size_t)m * K0 + k + kg * 8)
                    : zfrag;
    }
    bf16x8 bfr[4];
#pragma unroll
    for (int ct = 0; ct < 4; ++ct) {
      int o = col0 + ct * 16 + l15;
      bfr[ct] = *reinterpret_cast<const bf16x8*>(W0 + (size_t)o * K0 + k + kg * 8);
    }
#pragma unroll
    for (int rt = 0; rt < 2; ++rt)
#pragma unroll
      for (int ct = 0; ct < 4; ++ct)
        acc0[rt][ct] = __builtin_amdgcn_mfma_f32_16x16x32_bf16(afr[rt], bfr[ct],
                                                               acc0[rt][ct], 0, 0, 0);
  }

  // epilogue0 -> LDS (bf16, relu)
#pragma unroll
  for (int rt = 0; rt < 2; ++rt) {
#pragma unroll
    for (int ct = 0; ct < 4; ++ct) {
      int col = col0 + ct * 16 + l15;
      float bv = b0[col];
#pragma unroll
      for (int i = 0; i < 4; ++i) {
        int row_l = rt * 16 + kg * 4 + i;
        mid[row_l * MID_STRIDE + col] = bfbits(fmaxf(acc0[rt][ct][i] + bv, 0.0f));
      }
    }
  }
  __syncthreads();

  // ---- GEMM1 (A from LDS, K=256) ----
  f32x4 acc1[2][4];
#pragma unroll
  for (int rt = 0; rt < 2; ++rt)
#pragma unroll
    for (int ct = 0; ct < 4; ++ct) acc1[rt][ct] = 0.0f;

  for (int k = 0; k < D_H; k += 32) {
    bf16x8 afr[2];
#pragma unroll
    for (int rt = 0; rt < 2; ++rt) {
      int row_l = rt * 16 + l15;
      const unsigned short* p = mid + row_l * MID_STRIDE + k + kg * 8;
      bf16x4 lo = *reinterpret_cast<const bf16x4*>(p);      // ds_read_b64
      bf16x4 hi = *reinterpret_cast<const bf16x4*>(p + 4);  // ds_read_b64
      bf16x8 a;
#pragma unroll
      for (int j = 0; j < 4; ++j) {
        a[j] = lo[j];
        a[j + 4] = hi[j];
      }
      afr[rt] = a;
    }
    bf16x8 bfr[4];
#pragma unroll
    for (int ct = 0; ct < 4; ++ct) {
      int o = col0 + ct * 16 + l15;
      bfr[ct] = *reinterpret_cast<const bf16x8*>(W1 + (size_t)o * D_H + k + kg * 8);
    }
#pragma unroll
    for (int rt = 0; rt < 2; ++rt)
#pragma unroll
      for (int ct = 0; ct < 4; ++ct)
        acc1[rt][ct] = __builtin_amdgcn_mfma_f32_16x16x32_bf16(afr[rt], bfr[ct],
                                                               acc1[rt][ct], 0, 0, 0);
  }

  // epilogue1 -> global (relu)
#pragma unroll
  for (int rt = 0; rt < 2; ++rt) {
#pragma unroll
    for (int ct = 0; ct < 4; ++ct) {
      int col = col0 + ct * 16 + l15;
      float bv = b1[col];
#pragma unroll
      for (int i = 0; i < 4; ++i) {
        int row = row0 + rt * 16 + kg * 4 + i;
        if (row < Nrows) {
          float v = fmaxf(acc1[rt][ct][i] + bv, 0.0f);
          if (OUT_BF16)
            ((__hip_bfloat16*)Outp)[(size_t)row * D_H + col] = __float2bfloat16(v);
          else
            ((float*)Outp)[(size_t)row * D_H + col] = v;
        }
      }
    }
  }
}

extern "C" void kernel_launch(void* const* d_in, const int* in_sizes, int n_in,
                              void* d_out, int out_size, void* d_ws, size_t ws_size,
                              hipStream_t stream) {
  const float* x = (const float*)d_in[0];
  const int* ei = (const int*)d_in[1];  // [2, E]: row0 = src, row1 = dst
  const float* eps_all = (const float*)d_in[2];
  const float* w0_l0 = (const float*)d_in[3];
  const float* b0_l0 = (const float*)d_in[4];
  const float* w1_l0 = (const float*)d_in[5];
  const float* b1_l0 = (const float*)d_in[6];
  const float* w0_rest = (const float*)d_in[7];
  const float* b0_rest = (const float*)d_in[8];
  const float* w1_rest = (const float*)d_in[9];
  const float* b1_rest = (const float*)d_in[10];

  const int N = in_sizes[0] / D_IN;  // 50000
  const int E = in_sizes[1] / 2;     // 800000

  char* ws = (char*)d_ws;
  const size_t node_bf = (size_t)N * D_H * sizeof(unsigned short);  // 25.6 MB
  unsigned short* h = (unsigned short*)ws;       // layer outputs (bf16)
  unsigned short* pre = (unsigned short*)(ws + node_bf);
  char* p = ws + 2 * node_bf;
  __hip_bfloat16* wbf = (__hip_bfloat16*)p;
  p += 622592 * sizeof(__hip_bfloat16);
  int* deg = (int*)p;           // [N]
  int* cursor = deg + N;        // [N]
  int* row_start = cursor + N;  // [N]
  int* bsum = row_start + N;    // [64]
  int* csr = bsum + 64;         // [E]

  __hip_bfloat16* w0_l0_bf = wbf;
  __hip_bfloat16* w1_l0_bf = wbf + 32768;
  __hip_bfloat16* w0_rest_bf = wbf + 98304;
  __hip_bfloat16* w1_rest_bf = w0_rest_bf + 262144;

  conv_weights<<<(622592 + 255) / 256, 256, 0, stream>>>(w0_l0, w1_l0, w0_rest,
                                                         w1_rest, wbf);

  // CSR build
  const int nb = (N + 1023) / 1024;  // 49
  zero_ints<<<(2 * N + 255) / 256, 256, 0, stream>>>(deg, 2 * N);  // deg + cursor
  hist_kernel<<<(E + 255) / 256, 256, 0, stream>>>(ei, E, deg);
  block_sums<<<nb, 256, 0, stream>>>(deg, bsum, N);
  scan_bsums<<<1, 64, 0, stream>>>(bsum, nb);
  scan_apply<<<nb, 256, 0, stream>>>(deg, bsum, row_start, N);
  fill_kernel<<<(E + 255) / 256, 256, 0, stream>>>(ei, E, row_start, cursor, csr);

  const int gemmBlocks = (N + 31) / 32;
  const int aggBlocks = (N + 7) / 8;

  for (int layer = 0; layer < NLAYERS; ++layer) {
    const __hip_bfloat16* w0 =
        (layer == 0) ? w0_l0_bf : w0_rest_bf + (size_t)(layer - 1) * 65536;
    const float* b0 = (layer == 0) ? b0_l0 : b0_rest + (size_t)(layer - 1) * 256;
    const __hip_bfloat16* w1 =
        (layer == 0) ? w1_l0_bf : w1_rest_bf + (size_t)(layer - 1) * 65536;
    const float* b1 = (layer == 0) ? b1_l0 : b1_rest + (size_t)(layer - 1) * 256;

    if (layer == 0) {
      aggregate<D_IN, true><<<aggBlocks, 256, 0, stream>>>(
          x, csr, row_start, deg, eps_all, layer, pre, N);
      gin_mlp<D_IN, true><<<gemmBlocks, 256, 0, stream>>>(
          (const __hip_bfloat16*)pre, w0, b0, w1, b1, h, N);
    } else {
      aggregate<D_H, false><<<aggBlocks, 256, 0, stream>>>(
          h, csr, row_start, deg, eps_all, layer, pre, N);
      if (layer == NLAYERS - 1)
        gin_mlp<D_H, false><<<gemmBlocks, 256, 0, stream>>>(
            (const __hip_bfloat16*)pre, w0, b0, w1, b1, d_out, N);
      else
        gin_mlp<D_H, true><<<gemmBlocks, 256, 0, stream>>>(
            (const __hip_bfloat16*)pre, w0, b0, w1, b1, h, N);
    }
  }
}